// Round 13
// baseline (349.747 us; speedup 1.0000x reference)
//
#include <hip/hip_runtime.h>
#include <hip/hip_bf16.h>

#define NBATCH 32
#define Ls 1024
#define Ds 1024
#define Hs 1024

typedef float f32x4 __attribute__((ext_vector_type(4)));
typedef __bf16 v8bf __attribute__((ext_vector_type(8)));
typedef unsigned short u16x8 __attribute__((ext_vector_type(8)));
typedef unsigned short u16x4 __attribute__((ext_vector_type(4)));
typedef __hip_bfloat16 bf16;

__device__ __forceinline__ float bfbits2f(unsigned short h) {
  unsigned u = ((unsigned)h) << 16;
  return __builtin_bit_cast(float, u);
}
__device__ __forceinline__ unsigned short f2b(float x) {
  return __builtin_bit_cast(unsigned short, __float2bfloat16(x));
}
__device__ __forceinline__ u16x8 pack8(const float4& a, const float4& b, float s) {
  u16x8 r;
  r[0] = f2b(a.x * s); r[1] = f2b(a.y * s); r[2] = f2b(a.z * s); r[3] = f2b(a.w * s);
  r[4] = f2b(b.x * s); r[5] = f2b(b.y * s); r[6] = f2b(b.z * s); r[7] = f2b(b.w * s);
  return r;
}

// ---- q -> qn bf16 normalized; 2 rows/wave, grid-stride ----
__global__ __launch_bounds__(256) void k_convq(const float* __restrict__ q,
                                               bf16* __restrict__ qn) {
  const int w0 = ((int)blockIdx.x * 256 + (int)threadIdx.x) >> 6;   // 0..8191
  const int lane = threadIdx.x & 63;
  #pragma unroll
  for (int it = 0; it < 2; ++it) {
    const size_t r0 = ((size_t)(it * 8192 + w0)) * 2;               // rows r0, r0+1
    const float4* q0 = reinterpret_cast<const float4*>(q + r0 * Ds);
    float4 qv[2][4];
    #pragma unroll
    for (int rr = 0; rr < 2; ++rr)
      #pragma unroll
      for (int h = 0; h < 2; ++h) {
        qv[rr][h * 2 + 0] = q0[rr * 256 + h * 128 + lane * 2 + 0];
        qv[rr][h * 2 + 1] = q0[rr * 256 + h * 128 + lane * 2 + 1];
      }
    float sq0 = 0.f, sq1 = 0.f;
    #pragma unroll
    for (int p = 0; p < 4; ++p) {
      sq0 += qv[0][p].x*qv[0][p].x + qv[0][p].y*qv[0][p].y + qv[0][p].z*qv[0][p].z + qv[0][p].w*qv[0][p].w;
      sq1 += qv[1][p].x*qv[1][p].x + qv[1][p].y*qv[1][p].y + qv[1][p].z*qv[1][p].z + qv[1][p].w*qv[1][p].w;
    }
    #pragma unroll
    for (int o = 1; o < 64; o <<= 1) { sq0 += __shfl_xor(sq0, o); sq1 += __shfl_xor(sq1, o); }
    const float iq0 = 1.0f / sqrtf(sq0), iq1 = 1.0f / sqrtf(sq1);
    u16x8* qo = reinterpret_cast<u16x8*>(qn + r0 * Ds);
    qo[lane]        = pack8(qv[0][0], qv[0][1], iq0);
    qo[64 + lane]   = pack8(qv[0][2], qv[0][3], iq0);
    qo[128 + lane]  = pack8(qv[1][0], qv[1][1], iq1);
    qo[192 + lane]  = pack8(qv[1][2], qv[1][3], iq1);
  }
}

// ---- fused: k fp32 -> kb bf16 (row-major) + kT bf16 (transposed) + invk ----
__global__ __launch_bounds__(256) void k_convkT(const float* __restrict__ k,
                                                bf16* __restrict__ kb,
                                                bf16* __restrict__ kT,
                                                float* __restrict__ invk) {
  __shared__ float tile[64][65];
  __shared__ float red[4][16][16];     // [rr][jr][cg]
  const int b = blockIdx.y;
  const int j0 = blockIdx.x * 64;
  const int t = threadIdx.x;
  const int jr = t >> 4;               // 0..15
  const int cg = t & 15;
  const int c4 = cg * 4;
  const float* src = k + (size_t)b * Ls * Ds + (size_t)j0 * Ds;
  bf16* kbd = kb + (size_t)b * Ls * Ds + (size_t)j0 * Ds;
  bf16* kTd = kT + (size_t)b * Ds * Ls + j0;
  float ssq[4] = {0.f, 0.f, 0.f, 0.f};

  for (int dc = 0; dc < 16; ++dc) {
    const int d0 = dc * 64;
    float4 v[4];
    #pragma unroll
    for (int rr = 0; rr < 4; ++rr) {
      const int j = jr + rr * 16;
      v[rr] = *reinterpret_cast<const float4*>(&src[(size_t)j * Ds + d0 + c4]);
      ssq[rr] += v[rr].x*v[rr].x + v[rr].y*v[rr].y + v[rr].z*v[rr].z + v[rr].w*v[rr].w;
      u16x4 o = { f2b(v[rr].x), f2b(v[rr].y), f2b(v[rr].z), f2b(v[rr].w) };
      *reinterpret_cast<u16x4*>(&kbd[(size_t)j * Ds + d0 + c4]) = o;
    }
    __syncthreads();
    #pragma unroll
    for (int rr = 0; rr < 4; ++rr) {
      const int j = jr + rr * 16;
      tile[j][c4 + 0] = v[rr].x; tile[j][c4 + 1] = v[rr].y;
      tile[j][c4 + 2] = v[rr].z; tile[j][c4 + 3] = v[rr].w;
    }
    __syncthreads();
    #pragma unroll
    for (int rr = 0; rr < 4; ++rr) {
      const int dd = jr + rr * 16;
      u16x4 o = { f2b(tile[c4 + 0][dd]), f2b(tile[c4 + 1][dd]),
                  f2b(tile[c4 + 2][dd]), f2b(tile[c4 + 3][dd]) };
      *reinterpret_cast<u16x4*>(&kTd[(size_t)(d0 + dd) * Ls + c4]) = o;
    }
  }

  #pragma unroll
  for (int rr = 0; rr < 4; ++rr) red[rr][jr][cg] = ssq[rr];
  __syncthreads();
  if (t < 64) {
    const int r = (t & 15) + (t >> 4) * 16;
    float s = 0.f;
    #pragma unroll
    for (int c = 0; c < 16; ++c) s += red[t >> 4][t & 15][c];
    invk[(size_t)b * Ls + j0 + r] = 1.0f / sqrtf(s);
  }
}

// ---------------- W -> W2 = [wh | wh | wl] bf16, vector 4-wide ----------------
__global__ __launch_bounds__(256) void k_w2(const float* __restrict__ W,
                                            bf16* __restrict__ W2) {
  const size_t idx = (size_t)blockIdx.x * 256 + threadIdx.x;   // over H*D/4
  const size_t e0 = idx * 4;
  const size_t h = e0 >> 10, d = e0 & 1023;
  const float4 w = reinterpret_cast<const float4*>(W)[idx];
  u16x4 wh = { f2b(w.x), f2b(w.y), f2b(w.z), f2b(w.w) };
  u16x4 wl = { f2b(w.x - bfbits2f(wh[0])), f2b(w.y - bfbits2f(wh[1])),
               f2b(w.z - bfbits2f(wh[2])), f2b(w.w - bfbits2f(wh[3])) };
  bf16* row = W2 + h * 3072;
  *reinterpret_cast<u16x4*>(row + d) = wh;
  *reinterpret_cast<u16x4*>(row + 1024 + d) = wh;
  *reinterpret_cast<u16x4*>(row + 2048 + d) = wl;
}

// ======= 256x256, BK=64, 8 waves, counted-LGKMCNT overlap NT GEMM =======
// Mechanism: issue ALL 24 ds_reads of the K-tile up-front in pinned groups
// (a0[8], b01[4], b23[4], a1[8]); gate MFMA quadrants with counted lgkmcnt
// (12 / 8 / 0) so later read-groups EXECUTE under earlier MFMA clusters.
// Sync: mid-barrier after lgkmcnt(0) (all reads of dbuf d retired -> staging
// tile t+2 into dbuf d is safe), tile-end vmcnt(8|0)+barrier (counted ledger:
// outstanding = t+1's 8 old + t+2's 8 new -> vmcnt(8) drains t+1; when no
// stage this tile, vmcnt(0)). dbuf(t) = t&1.
template<int KT, int MODE>
__global__ __launch_bounds__(512) void k_gemm256(
    const bf16* __restrict__ A, const bf16* __restrict__ B,
    void* __restrict__ Cv, const float* __restrict__ scale,
    int lda, int ldb, int ldc, int nb,
    size_t sA, size_t sB, size_t zA, size_t zB, size_t zC, size_t zS)
{
  __shared__ bf16 lds[2][2][256 * 64];
  const int tid = threadIdx.x;
  const int lane = tid & 63;
  const int wid = tid >> 6;
  const int wr = wid >> 2;            // 0..1  (M)
  const int wc = wid & 3;             // 0..3  (N)
  const size_t m0 = (size_t)blockIdx.y * 256;
  const size_t n0 = (size_t)blockIdx.x * 256;
  const bf16* Az = A + (size_t)blockIdx.z * zA;
  const bf16* Bz = B + (size_t)blockIdx.z * zB;

  const int srow = tid >> 3;          // 0..63 row-within-chunk
  const int sslot = tid & 7;          // 16B slot
  f32x4 acc[8][4] = {};

  auto stageChunk = [&](int tt, int ab, int c, int buf) {
    const int bz = tt / KT;
    const int k0 = (tt - bz * KT) * 64;
    const int row = c * 64 + srow;
    const int ksl = (sslot ^ (row & 7)) * 8;
    const bf16* src = (ab == 0)
        ? (Az + (size_t)bz * sA + (m0 + row) * lda + k0 + ksl)
        : (Bz + (size_t)bz * sB + (n0 + row) * ldb + k0 + ksl);
    __builtin_amdgcn_global_load_lds(
        (const __attribute__((address_space(1))) void*)src,
        (__attribute__((address_space(3))) void*)(&lds[buf][ab][c * 4096 + tid * 8]), 16, 0, 0);
  };

  const int rsel = lane & 15, qd = lane >> 4;
  v8bf a0[4][2], a1[4][2], b[4][2];

  auto readAinto = [&](v8bf (&dst)[4][2], const bf16* As, int mh) {
    #pragma unroll
    for (int m = 0; m < 4; ++m) {
      const int r = wr * 128 + mh * 64 + m * 16 + rsel;
      #pragma unroll
      for (int h = 0; h < 2; ++h) {
        const int s = (h * 4 + qd) ^ (r & 7);
        dst[m][h] = *reinterpret_cast<const v8bf*>(reinterpret_cast<const char*>(As) + r * 128 + s * 16);
      }
    }
  };
  auto readB2 = [&](const bf16* Bs, int npair) {
    #pragma unroll
    for (int n = 0; n < 2; ++n) {
      const int r = wc * 64 + (npair * 2 + n) * 16 + rsel;
      #pragma unroll
      for (int h = 0; h < 2; ++h) {
        const int s = (h * 4 + qd) ^ (r & 7);
        b[npair * 2 + n][h] = *reinterpret_cast<const v8bf*>(reinterpret_cast<const char*>(Bs) + r * 128 + s * 16);
      }
    }
  };
  auto mfmaQ = [&](v8bf (&aa)[4][2], int mh, int npair) {  // 16 MFMA
    __builtin_amdgcn_s_setprio(1);
    #pragma unroll
    for (int m = 0; m < 4; ++m)
      #pragma unroll
      for (int n = 0; n < 2; ++n) {
        const int mi = mh * 4 + m, ni = npair * 2 + n;
        acc[mi][ni] = __builtin_amdgcn_mfma_f32_16x16x32_bf16(aa[m][0], b[ni][0], acc[mi][ni], 0, 0, 0);
        acc[mi][ni] = __builtin_amdgcn_mfma_f32_16x16x32_bf16(aa[m][1], b[ni][1], acc[mi][ni], 0, 0, 0);
      }
    __builtin_amdgcn_s_setprio(0);
  };

  const int T = KT * nb;              // total K-tiles (>= 4, even)

  // prologue: tile 0 -> dbuf0, tile 1 -> dbuf1 (8 loads each)
  #pragma unroll
  for (int c = 0; c < 4; ++c) stageChunk(0, 0, c, 0);
  #pragma unroll
  for (int c = 0; c < 4; ++c) stageChunk(0, 1, c, 0);
  #pragma unroll
  for (int c = 0; c < 4; ++c) stageChunk(1, 0, c, 1);
  #pragma unroll
  for (int c = 0; c < 4; ++c) stageChunk(1, 1, c, 1);
  asm volatile("s_waitcnt vmcnt(8)" ::: "memory");    // tile 0 resident; tile 1 may fly
  __builtin_amdgcn_s_barrier();

  for (int t = 0; t < T; ++t) {
    const int d = t & 1;
    const bf16* As = lds[d][0];
    const bf16* Bs = lds[d][1];
    const int u = t + 2;
    const bool st = (u < T);

    // issue ALL tile reads in pinned groups: a0(8) b01(4) | b23(4) | a1(8)
    readAinto(a0, As, 0);
    readB2(Bs, 0);
    __builtin_amdgcn_sched_barrier(0);
    readB2(Bs, 1);
    __builtin_amdgcn_sched_barrier(0);
    readAinto(a1, As, 1);
    __builtin_amdgcn_sched_barrier(0);

    // Q1: needs a0+b01 (first 12 reads) -> allow 12 newest (b23+a1) in flight
    asm volatile("s_waitcnt lgkmcnt(12)" ::: "memory");
    __builtin_amdgcn_sched_barrier(0);
    mfmaQ(a0, 0, 0);
    // Q2: needs b23 (first 16) -> allow 8 newest (a1) in flight
    asm volatile("s_waitcnt lgkmcnt(8)" ::: "memory");
    __builtin_amdgcn_sched_barrier(0);
    mfmaQ(a0, 0, 1);
    // Q3/Q4: need a1 -> drain; then block-wide "all reads retired" barrier
    asm volatile("s_waitcnt lgkmcnt(0)" ::: "memory");
    __builtin_amdgcn_sched_barrier(0);
    __builtin_amdgcn_s_barrier();
    // stage tile t+2 into dbuf d (regions now fully consumed); DMA overlaps Q3/Q4
    if (st) {
      stageChunk(u, 0, 0, d); stageChunk(u, 0, 1, d);
      stageChunk(u, 0, 2, d); stageChunk(u, 0, 3, d);
      stageChunk(u, 1, 0, d); stageChunk(u, 1, 1, d);
      stageChunk(u, 1, 2, d); stageChunk(u, 1, 3, d);
    }
    __builtin_amdgcn_sched_barrier(0);
    mfmaQ(a1, 1, 1);
    mfmaQ(a1, 1, 0);
    if (t < T - 1) {
      if (st) { asm volatile("s_waitcnt vmcnt(8)" ::: "memory"); }   // drain tile t+1
      else    { asm volatile("s_waitcnt vmcnt(0)" ::: "memory"); }   // tail: drain all
      __builtin_amdgcn_s_barrier();
    }
  }

  // epilogue: C/D layout col=lane&15, row=(lane>>4)*4+reg
  if (MODE == 0) {
    float* Cz = (float*)Cv + (size_t)blockIdx.z * zC;
    #pragma unroll
    for (int m = 0; m < 8; ++m) {
      const size_t ri = m0 + wr * 128 + m * 16 + (size_t)((lane >> 4) * 4);
      #pragma unroll
      for (int n = 0; n < 4; ++n) {
        const size_t cj = n0 + wc * 64 + n * 16 + (lane & 15);
        #pragma unroll
        for (int r = 0; r < 4; ++r)
          Cz[(ri + r) * ldc + cj] = acc[m][n][r];
      }
    }
  } else {
    bf16* Cz = (bf16*)Cv + (size_t)blockIdx.z * zC;
    const float* Sz = scale + (size_t)blockIdx.z * zS;
    #pragma unroll
    for (int m = 0; m < 8; ++m) {
      const size_t ri = m0 + wr * 128 + m * 16 + (size_t)((lane >> 4) * 4);
      const float4 ik = *reinterpret_cast<const float4*>(Sz + ri);
      #pragma unroll
      for (int n = 0; n < 4; ++n) {
        const size_t cj = n0 + wc * 64 + n * 16 + (lane & 15);
        Cz[(ri + 0) * ldc + cj] = __float2bfloat16(acc[m][n][0] * ik.x);
        Cz[(ri + 1) * ldc + cj] = __float2bfloat16(acc[m][n][1] * ik.y);
        Cz[(ri + 2) * ldc + cj] = __float2bfloat16(acc[m][n][2] * ik.z);
        Cz[(ri + 3) * ldc + cj] = __float2bfloat16(acc[m][n][3] * ik.w);
      }
    }
  }
}

// ---------------- 128x128 NT GEMM (kept for the small x-GEMM) ----------------
__global__ __launch_bounds__(256) void k_gemm_nt(
    const bf16* __restrict__ A, const bf16* __restrict__ B,
    float* __restrict__ C,
    int lda, int ldb, int ldc, int K,
    size_t zA, size_t zB, size_t zC)
{
  __shared__ bf16 As[128 * 32];
  __shared__ bf16 Bs[128 * 32];
  const int tid = threadIdx.x;
  const int lane = tid & 63;
  const int wc = (tid >> 6) & 1;
  const int wr = (tid >> 7) & 1;
  const size_t m0 = (size_t)blockIdx.y * 128;
  const size_t n0 = (size_t)blockIdx.x * 128;
  const bf16* Az = A + (size_t)blockIdx.z * zA;
  const bf16* Bz = B + (size_t)blockIdx.z * zB;
  float* Cz = C + (size_t)blockIdx.z * zC;
  f32x4 acc[4][4] = {};

  const int beta0 = tid * 16;
  const int row0 = tid >> 2;
  const int kk0 = ((tid & 3) ^ ((row0 >> 1) & 3)) * 8;
  const int sw = (((lane >> 4) ^ ((lane >> 1) & 3)) << 4);
  const int rsel = lane & 15;

  for (int k0 = 0; k0 < K; k0 += 32) {
    __syncthreads();
    __builtin_amdgcn_global_load_lds(
        (const __attribute__((address_space(1))) void*)(Az + (m0 + row0) * lda + (k0 + kk0)),
        (__attribute__((address_space(3))) void*)(&As[beta0 / 2]), 16, 0, 0);
    __builtin_amdgcn_global_load_lds(
        (const __attribute__((address_space(1))) void*)(Az + (m0 + row0 + 64) * lda + (k0 + kk0)),
        (__attribute__((address_space(3))) void*)(&As[beta0 / 2 + 2048]), 16, 0, 0);
    __builtin_amdgcn_global_load_lds(
        (const __attribute__((address_space(1))) void*)(Bz + (n0 + row0) * ldb + (k0 + kk0)),
        (__attribute__((address_space(3))) void*)(&Bs[beta0 / 2]), 16, 0, 0);
    __builtin_amdgcn_global_load_lds(
        (const __attribute__((address_space(1))) void*)(Bz + (n0 + row0 + 64) * ldb + (k0 + kk0)),
        (__attribute__((address_space(3))) void*)(&Bs[beta0 / 2 + 2048]), 16, 0, 0);
    __syncthreads();

    v8bf af[4], bg[4];
    #pragma unroll
    for (int m = 0; m < 4; ++m) {
      const int rA = wr * 64 + m * 16 + rsel;
      af[m] = *reinterpret_cast<const v8bf*>(reinterpret_cast<const char*>(As) + rA * 64 + sw);
      const int rB = wc * 64 + m * 16 + rsel;
      bg[m] = *reinterpret_cast<const v8bf*>(reinterpret_cast<const char*>(Bs) + rB * 64 + sw);
    }
    #pragma unroll
    for (int m = 0; m < 4; ++m)
      #pragma unroll
      for (int n = 0; n < 4; ++n)
        acc[m][n] = __builtin_amdgcn_mfma_f32_16x16x32_bf16(af[m], bg[n], acc[m][n], 0, 0, 0);
  }

  #pragma unroll
  for (int m = 0; m < 4; ++m) {
    const size_t ri = m0 + wr * 64 + m * 16 + ((lane >> 4) * 4);
    #pragma unroll
    for (int n = 0; n < 4; ++n) {
      const size_t cj = n0 + wc * 64 + n * 16 + (lane & 15);
      #pragma unroll
      for (int r = 0; r < 4; ++r)
        Cz[(ri + r) * ldc + cj] = acc[m][n][r];
    }
  }
}

// ---- softmax over rows (bf16 scores in, no-max: cosine-bounded), grid-stride ----
__global__ __launch_bounds__(256) void k_softmax(const bf16* __restrict__ sc,
                                                 float* __restrict__ attn,
                                                 bf16* __restrict__ abf) {
  const int wave = ((int)blockIdx.x * 256 + (int)threadIdx.x) >> 6;  // 0..8191
  const int lane = threadIdx.x & 63;
  for (int i = 0; i < 4; ++i) {
    const size_t row = (size_t)wave * 4 + i;
    const u16x8* sr = reinterpret_cast<const u16x8*>(sc + row * Ls);
    const u16x8 s0 = sr[lane], s1 = sr[lane + 64];
    float e[16];
    float ss = 0.f;
    #pragma unroll
    for (int j = 0; j < 8; ++j) { e[j] = __expf(bfbits2f(s0[j])); ss += e[j]; }
    #pragma unroll
    for (int j = 0; j < 8; ++j) { e[8 + j] = __expf(bfbits2f(s1[j])); ss += e[8 + j]; }
    #pragma unroll
    for (int o = 1; o < 64; o <<= 1) ss += __shfl_xor(ss, o);
    const float inv = 1.0f / ss;
    #pragma unroll
    for (int j = 0; j < 16; ++j) e[j] *= inv;
    float4* ar = reinterpret_cast<float4*>(attn + row * Ls);
    float4 a0 = {e[0], e[1], e[2], e[3]},   a1 = {e[4], e[5], e[6], e[7]};
    float4 a2 = {e[8], e[9], e[10], e[11]}, a3 = {e[12], e[13], e[14], e[15]};
    ar[lane * 2 + 0] = a0;  ar[lane * 2 + 1] = a1;
    ar[128 + lane * 2 + 0] = a2;  ar[128 + lane * 2 + 1] = a3;
    u16x8* ab8 = reinterpret_cast<u16x8*>(abf + row * Ls);
    u16x8 b0, b1;
    #pragma unroll
    for (int j = 0; j < 8; ++j) { b0[j] = f2b(e[j]); b1[j] = f2b(e[8 + j]); }
    ab8[lane] = b0;
    ab8[64 + lane] = b1;
  }
}

// ---------------- reduce split-K partials -> A2 = [ah | al | ah] ----------------
__global__ __launch_bounds__(256) void k_reduce(const float* __restrict__ part,
                                                bf16* __restrict__ A2) {
  const size_t idx = (size_t)blockIdx.x * 256 + threadIdx.x;   // over L*D/4
  float4 s = {0.f, 0.f, 0.f, 0.f};
  #pragma unroll
  for (int g = 0; g < 16; ++g) {
    const float4 p = reinterpret_cast<const float4*>(part + (size_t)g * (Ls * Ds))[idx];
    s.x += p.x; s.y += p.y; s.z += p.z; s.w += p.w;
  }
  const size_t e0 = idx * 4;
  const size_t i = e0 >> 10, d = e0 & 1023;
  u16x4 h = { f2b(s.x), f2b(s.y), f2b(s.z), f2b(s.w) };
  u16x4 l = { f2b(s.x - bfbits2f(h[0])), f2b(s.y - bfbits2f(h[1])),
              f2b(s.z - bfbits2f(h[2])), f2b(s.w - bfbits2f(h[3])) };
  bf16* row = A2 + i * 3072;
  *reinterpret_cast<u16x4*>(row + d) = h;
  *reinterpret_cast<u16x4*>(row + 1024 + d) = l;
  *reinterpret_cast<u16x4*>(row + 2048 + d) = h;
}

// ---------------- reduce x split-K partials + bias + relu ----------------
__global__ __launch_bounds__(256) void k_reduce2(const float* __restrict__ part2,
                                                 const float* __restrict__ bias,
                                                 float* __restrict__ xout) {
  const size_t idx = (size_t)blockIdx.x * 256 + threadIdx.x;   // over L*H/4
  float4 s = {0.f, 0.f, 0.f, 0.f};
  #pragma unroll
  for (int g = 0; g < 4; ++g) {
    const float4 p = reinterpret_cast<const float4*>(part2 + (size_t)g * (Ls * Hs))[idx];
    s.x += p.x; s.y += p.y; s.z += p.z; s.w += p.w;
  }
  const size_t h0 = (idx * 4) & 1023;
  const float4 bv = *reinterpret_cast<const float4*>(bias + h0);
  s.x = fmaxf(s.x + bv.x, 0.f); s.y = fmaxf(s.y + bv.y, 0.f);
  s.z = fmaxf(s.z + bv.z, 0.f); s.w = fmaxf(s.w + bv.w, 0.f);
  reinterpret_cast<float4*>(xout)[idx] = s;
}

extern "C" void kernel_launch(void* const* d_in, const int* in_sizes, int n_in,
                              void* d_out, int out_size, void* d_ws, size_t ws_size,
                              hipStream_t stream) {
  const float* q = (const float*)d_in[0];
  const float* k = (const float*)d_in[1];
  const float* W = (const float*)d_in[2];
  const float* bias = (const float*)d_in[3];
  float* xout = (float*)d_out;                        // [1024][1024]
  float* attn = (float*)d_out + (size_t)Ls * Hs;      // [32][1024][1024]

  char* w = (char*)d_ws;
  bf16* qn    = (bf16*)w;                             // 64 MB; reused as abf
  bf16* kb    = (bf16*)(w + ((size_t)64 << 20));      // 64 MB raw keys; reused as part
  bf16* kT    = (bf16*)(w + ((size_t)128 << 20));     // 64 MB; reused as part2
  bf16* sc_bf = (bf16*)(w + ((size_t)192 << 20));     // 64 MB bf16 scores
  bf16* W2    = (bf16*)(w + ((size_t)256 << 20));     // 6 MB
  bf16* A2    = (bf16*)(w + ((size_t)263 << 20));     // 6 MB
  float* invk = (float*)(w + ((size_t)270 << 20));    // 128 KB
  float* part  = (float*)kb;                          // 64 MB (16 groups x 4 MB)
  float* part2 = (float*)kT;                          // 16 MB (4 groups x 4 MB)
  bf16* abf = qn;

  k_convq<<<2048, 256, 0, stream>>>(q, qn);
  k_convkT<<<dim3(16, NBATCH), 256, 0, stream>>>(k, kb, kT, invk);
  k_w2<<<(Hs * Ds / 4) / 256, 256, 0, stream>>>(W, W2);

  // scores[b][i][j] = (kb_b[i,:] . qn_b[j,:]) * invk[b][i] -> bf16 ws
  k_gemm256<16, 1><<<dim3(4, 4, NBATCH), 512, 0, stream>>>(kb, qn, sc_bf, invk,
      Ds, Ds, Ls, 1,
      (size_t)Ls * Ds, (size_t)Ls * Ds,
      (size_t)Ls * Ds, (size_t)Ls * Ds, (size_t)Ls * Ls, (size_t)Ls);

  k_softmax<<<2048, 256, 0, stream>>>(sc_bf, attn, abf);

  // out partials: 16 z-groups x 2 batches each
  k_gemm256<16, 0><<<dim3(4, 4, 16), 512, 0, stream>>>(abf, kT, part, nullptr,
      Ls, Ls, Ds, 2,
      (size_t)Ls * Ls, (size_t)Ls * Ds,
      (size_t)2 * Ls * Ls, (size_t)2 * Ls * Ds, (size_t)Ls * Ds, 0);

  k_reduce<<<(Ls * Ds / 4) / 256, 256, 0, stream>>>(part, A2);

  // x partials: split-K over 4 z-groups, K=768 each (A2/W2 are K=3072 hi/lo-split)
  k_gemm_nt<<<dim3(8, 8, 4), 256, 0, stream>>>(A2, W2, part2,
      3072, 3072, Hs, 768, 768, 768, (size_t)Ls * Hs);

  k_reduce2<<<(Ls * Hs / 4) / 256, 256, 0, stream>>>(part2, bias, xout);
}

// Round 14
// 342.998 us; speedup vs baseline: 1.0197x; 1.0197x over previous
//
#include <hip/hip_runtime.h>
#include <hip/hip_bf16.h>

#define NBATCH 32
#define Ls 1024
#define Ds 1024
#define Hs 1024

typedef float f32x4 __attribute__((ext_vector_type(4)));
typedef __bf16 v8bf __attribute__((ext_vector_type(8)));
typedef unsigned short u16x8 __attribute__((ext_vector_type(8)));
typedef unsigned short u16x4 __attribute__((ext_vector_type(4)));
typedef __hip_bfloat16 bf16;

__device__ __forceinline__ float bfbits2f(unsigned short h) {
  unsigned u = ((unsigned)h) << 16;
  return __builtin_bit_cast(float, u);
}
__device__ __forceinline__ unsigned short f2b(float x) {
  return __builtin_bit_cast(unsigned short, __float2bfloat16(x));
}
__device__ __forceinline__ u16x8 pack8(const float4& a, const float4& b, float s) {
  u16x8 r;
  r[0] = f2b(a.x * s); r[1] = f2b(a.y * s); r[2] = f2b(a.z * s); r[3] = f2b(a.w * s);
  r[4] = f2b(b.x * s); r[5] = f2b(b.y * s); r[6] = f2b(b.z * s); r[7] = f2b(b.w * s);
  return r;
}

// ---- q -> qn bf16 normalized; 2 rows/wave, grid-stride ----
__global__ __launch_bounds__(256) void k_convq(const float* __restrict__ q,
                                               bf16* __restrict__ qn) {
  const int w0 = ((int)blockIdx.x * 256 + (int)threadIdx.x) >> 6;   // 0..8191
  const int lane = threadIdx.x & 63;
  #pragma unroll
  for (int it = 0; it < 2; ++it) {
    const size_t r0 = ((size_t)(it * 8192 + w0)) * 2;               // rows r0, r0+1
    const float4* q0 = reinterpret_cast<const float4*>(q + r0 * Ds);
    float4 qv[2][4];
    #pragma unroll
    for (int rr = 0; rr < 2; ++rr)
      #pragma unroll
      for (int h = 0; h < 2; ++h) {
        qv[rr][h * 2 + 0] = q0[rr * 256 + h * 128 + lane * 2 + 0];
        qv[rr][h * 2 + 1] = q0[rr * 256 + h * 128 + lane * 2 + 1];
      }
    float sq0 = 0.f, sq1 = 0.f;
    #pragma unroll
    for (int p = 0; p < 4; ++p) {
      sq0 += qv[0][p].x*qv[0][p].x + qv[0][p].y*qv[0][p].y + qv[0][p].z*qv[0][p].z + qv[0][p].w*qv[0][p].w;
      sq1 += qv[1][p].x*qv[1][p].x + qv[1][p].y*qv[1][p].y + qv[1][p].z*qv[1][p].z + qv[1][p].w*qv[1][p].w;
    }
    #pragma unroll
    for (int o = 1; o < 64; o <<= 1) { sq0 += __shfl_xor(sq0, o); sq1 += __shfl_xor(sq1, o); }
    const float iq0 = 1.0f / sqrtf(sq0), iq1 = 1.0f / sqrtf(sq1);
    u16x8* qo = reinterpret_cast<u16x8*>(qn + r0 * Ds);
    qo[lane]        = pack8(qv[0][0], qv[0][1], iq0);
    qo[64 + lane]   = pack8(qv[0][2], qv[0][3], iq0);
    qo[128 + lane]  = pack8(qv[1][0], qv[1][1], iq1);
    qo[192 + lane]  = pack8(qv[1][2], qv[1][3], iq1);
  }
}

// ---- fused: k fp32 -> kb bf16 (row-major) + kT bf16 (transposed) + invk ----
__global__ __launch_bounds__(256) void k_convkT(const float* __restrict__ k,
                                                bf16* __restrict__ kb,
                                                bf16* __restrict__ kT,
                                                float* __restrict__ invk) {
  __shared__ float tile[64][65];
  __shared__ float red[4][16][16];     // [rr][jr][cg]
  const int b = blockIdx.y;
  const int j0 = blockIdx.x * 64;
  const int t = threadIdx.x;
  const int jr = t >> 4;               // 0..15
  const int cg = t & 15;
  const int c4 = cg * 4;
  const float* src = k + (size_t)b * Ls * Ds + (size_t)j0 * Ds;
  bf16* kbd = kb + (size_t)b * Ls * Ds + (size_t)j0 * Ds;
  bf16* kTd = kT + (size_t)b * Ds * Ls + j0;
  float ssq[4] = {0.f, 0.f, 0.f, 0.f};

  for (int dc = 0; dc < 16; ++dc) {
    const int d0 = dc * 64;
    float4 v[4];
    #pragma unroll
    for (int rr = 0; rr < 4; ++rr) {
      const int j = jr + rr * 16;
      v[rr] = *reinterpret_cast<const float4*>(&src[(size_t)j * Ds + d0 + c4]);
      ssq[rr] += v[rr].x*v[rr].x + v[rr].y*v[rr].y + v[rr].z*v[rr].z + v[rr].w*v[rr].w;
      u16x4 o = { f2b(v[rr].x), f2b(v[rr].y), f2b(v[rr].z), f2b(v[rr].w) };
      *reinterpret_cast<u16x4*>(&kbd[(size_t)j * Ds + d0 + c4]) = o;
    }
    __syncthreads();
    #pragma unroll
    for (int rr = 0; rr < 4; ++rr) {
      const int j = jr + rr * 16;
      tile[j][c4 + 0] = v[rr].x; tile[j][c4 + 1] = v[rr].y;
      tile[j][c4 + 2] = v[rr].z; tile[j][c4 + 3] = v[rr].w;
    }
    __syncthreads();
    #pragma unroll
    for (int rr = 0; rr < 4; ++rr) {
      const int dd = jr + rr * 16;
      u16x4 o = { f2b(tile[c4 + 0][dd]), f2b(tile[c4 + 1][dd]),
                  f2b(tile[c4 + 2][dd]), f2b(tile[c4 + 3][dd]) };
      *reinterpret_cast<u16x4*>(&kTd[(size_t)(d0 + dd) * Ls + c4]) = o;
    }
  }

  #pragma unroll
  for (int rr = 0; rr < 4; ++rr) red[rr][jr][cg] = ssq[rr];
  __syncthreads();
  if (t < 64) {
    const int r = (t & 15) + (t >> 4) * 16;
    float s = 0.f;
    #pragma unroll
    for (int c = 0; c < 16; ++c) s += red[t >> 4][t & 15][c];
    invk[(size_t)b * Ls + j0 + r] = 1.0f / sqrtf(s);
  }
}

// ---------------- W -> W2 = [wh | wh | wl] bf16, vector 4-wide ----------------
__global__ __launch_bounds__(256) void k_w2(const float* __restrict__ W,
                                            bf16* __restrict__ W2) {
  const size_t idx = (size_t)blockIdx.x * 256 + threadIdx.x;   // over H*D/4
  const size_t e0 = idx * 4;
  const size_t h = e0 >> 10, d = e0 & 1023;
  const float4 w = reinterpret_cast<const float4*>(W)[idx];
  u16x4 wh = { f2b(w.x), f2b(w.y), f2b(w.z), f2b(w.w) };
  u16x4 wl = { f2b(w.x - bfbits2f(wh[0])), f2b(w.y - bfbits2f(wh[1])),
               f2b(w.z - bfbits2f(wh[2])), f2b(w.w - bfbits2f(wh[3])) };
  bf16* row = W2 + h * 3072;
  *reinterpret_cast<u16x4*>(row + d) = wh;
  *reinterpret_cast<u16x4*>(row + 1024 + d) = wh;
  *reinterpret_cast<u16x4*>(row + 2048 + d) = wl;
}

// ======= 256x256, BK=64, 8 waves, counted-LGKMCNT overlap NT GEMM =======
// + XCD-affinity swizzle: flat 1D grid; bz = (bid&7) + 8*(bid>>7), w = (bid>>3)&15,
//   (bx,by) = (w&3, w>>2). Bijective; all 16 blocks of batch/group bz land on XCD
//   bz%8 (dispatch round-robin), whose 4MB L2 holds that batch's A+B panels (4MB).
// Schedule: issue ALL 24 ds_reads up-front in pinned groups; gate MFMA quadrants
// with counted lgkmcnt (12/8/0); mid-barrier after lgkmcnt(0) -> stage t+2 into
// same dbuf; tile-end vmcnt(8|0)+barrier. dbuf(t)=t&1.
template<int KT, int MODE>
__global__ __launch_bounds__(512) void k_gemm256(
    const bf16* __restrict__ A, const bf16* __restrict__ B,
    void* __restrict__ Cv, const float* __restrict__ scale,
    int lda, int ldb, int ldc, int nb,
    size_t sA, size_t sB, size_t zA, size_t zB, size_t zC, size_t zS)
{
  __shared__ bf16 lds[2][2][256 * 64];
  const int tid = threadIdx.x;
  const int lane = tid & 63;
  const int wid = tid >> 6;
  const int wr = wid >> 2;            // 0..1  (M)
  const int wc = wid & 3;             // 0..3  (N)
  // XCD-affinity decode
  const int bid = blockIdx.x;
  const int bz = (bid & 7) + 8 * (bid >> 7);
  const int wq = (bid >> 3) & 15;
  const size_t n0 = (size_t)(wq & 3) * 256;
  const size_t m0 = (size_t)(wq >> 2) * 256;
  const bf16* Az = A + (size_t)bz * zA;
  const bf16* Bz = B + (size_t)bz * zB;

  const int srow = tid >> 3;          // 0..63 row-within-chunk
  const int sslot = tid & 7;          // 16B slot
  f32x4 acc[8][4] = {};

  auto stageChunk = [&](int tt, int ab, int c, int buf) {
    const int bb = tt / KT;
    const int k0 = (tt - bb * KT) * 64;
    const int row = c * 64 + srow;
    const int ksl = (sslot ^ (row & 7)) * 8;
    const bf16* src = (ab == 0)
        ? (Az + (size_t)bb * sA + (m0 + row) * lda + k0 + ksl)
        : (Bz + (size_t)bb * sB + (n0 + row) * ldb + k0 + ksl);
    __builtin_amdgcn_global_load_lds(
        (const __attribute__((address_space(1))) void*)src,
        (__attribute__((address_space(3))) void*)(&lds[buf][ab][c * 4096 + tid * 8]), 16, 0, 0);
  };

  const int rsel = lane & 15, qd = lane >> 4;
  v8bf a0[4][2], a1[4][2], b[4][2];

  auto readAinto = [&](v8bf (&dst)[4][2], const bf16* As, int mh) {
    #pragma unroll
    for (int m = 0; m < 4; ++m) {
      const int r = wr * 128 + mh * 64 + m * 16 + rsel;
      #pragma unroll
      for (int h = 0; h < 2; ++h) {
        const int s = (h * 4 + qd) ^ (r & 7);
        dst[m][h] = *reinterpret_cast<const v8bf*>(reinterpret_cast<const char*>(As) + r * 128 + s * 16);
      }
    }
  };
  auto readB2 = [&](const bf16* Bs, int npair) {
    #pragma unroll
    for (int n = 0; n < 2; ++n) {
      const int r = wc * 64 + (npair * 2 + n) * 16 + rsel;
      #pragma unroll
      for (int h = 0; h < 2; ++h) {
        const int s = (h * 4 + qd) ^ (r & 7);
        b[npair * 2 + n][h] = *reinterpret_cast<const v8bf*>(reinterpret_cast<const char*>(Bs) + r * 128 + s * 16);
      }
    }
  };
  auto mfmaQ = [&](v8bf (&aa)[4][2], int mh, int npair) {  // 16 MFMA
    __builtin_amdgcn_s_setprio(1);
    #pragma unroll
    for (int m = 0; m < 4; ++m)
      #pragma unroll
      for (int n = 0; n < 2; ++n) {
        const int mi = mh * 4 + m, ni = npair * 2 + n;
        acc[mi][ni] = __builtin_amdgcn_mfma_f32_16x16x32_bf16(aa[m][0], b[ni][0], acc[mi][ni], 0, 0, 0);
        acc[mi][ni] = __builtin_amdgcn_mfma_f32_16x16x32_bf16(aa[m][1], b[ni][1], acc[mi][ni], 0, 0, 0);
      }
    __builtin_amdgcn_s_setprio(0);
  };

  const int T = KT * nb;              // total K-tiles (>= 4, even)

  // prologue: tile 0 -> dbuf0, tile 1 -> dbuf1 (8 loads each)
  #pragma unroll
  for (int c = 0; c < 4; ++c) stageChunk(0, 0, c, 0);
  #pragma unroll
  for (int c = 0; c < 4; ++c) stageChunk(0, 1, c, 0);
  #pragma unroll
  for (int c = 0; c < 4; ++c) stageChunk(1, 0, c, 1);
  #pragma unroll
  for (int c = 0; c < 4; ++c) stageChunk(1, 1, c, 1);
  asm volatile("s_waitcnt vmcnt(8)" ::: "memory");    // tile 0 resident; tile 1 may fly
  __builtin_amdgcn_s_barrier();

  for (int t = 0; t < T; ++t) {
    const int d = t & 1;
    const bf16* As = lds[d][0];
    const bf16* Bs = lds[d][1];
    const int u = t + 2;
    const bool st = (u < T);

    // issue ALL tile reads in pinned groups: a0(8) b01(4) | b23(4) | a1(8)
    readAinto(a0, As, 0);
    readB2(Bs, 0);
    __builtin_amdgcn_sched_barrier(0);
    readB2(Bs, 1);
    __builtin_amdgcn_sched_barrier(0);
    readAinto(a1, As, 1);
    __builtin_amdgcn_sched_barrier(0);

    // Q1: needs a0+b01 (first 12 reads) -> allow 12 newest (b23+a1) in flight
    asm volatile("s_waitcnt lgkmcnt(12)" ::: "memory");
    __builtin_amdgcn_sched_barrier(0);
    mfmaQ(a0, 0, 0);
    // Q2: needs b23 (first 16) -> allow 8 newest (a1) in flight
    asm volatile("s_waitcnt lgkmcnt(8)" ::: "memory");
    __builtin_amdgcn_sched_barrier(0);
    mfmaQ(a0, 0, 1);
    // Q3/Q4: need a1 -> drain; then block-wide "all reads retired" barrier
    asm volatile("s_waitcnt lgkmcnt(0)" ::: "memory");
    __builtin_amdgcn_sched_barrier(0);
    __builtin_amdgcn_s_barrier();
    // stage tile t+2 into dbuf d (regions now fully consumed); DMA overlaps Q3/Q4
    if (st) {
      stageChunk(u, 0, 0, d); stageChunk(u, 0, 1, d);
      stageChunk(u, 0, 2, d); stageChunk(u, 0, 3, d);
      stageChunk(u, 1, 0, d); stageChunk(u, 1, 1, d);
      stageChunk(u, 1, 2, d); stageChunk(u, 1, 3, d);
    }
    __builtin_amdgcn_sched_barrier(0);
    mfmaQ(a1, 1, 1);
    mfmaQ(a1, 1, 0);
    if (t < T - 1) {
      if (st) { asm volatile("s_waitcnt vmcnt(8)" ::: "memory"); }   // drain tile t+1
      else    { asm volatile("s_waitcnt vmcnt(0)" ::: "memory"); }   // tail: drain all
      __builtin_amdgcn_s_barrier();
    }
  }

  // epilogue: C/D layout col=lane&15, row=(lane>>4)*4+reg
  if (MODE == 0) {
    float* Cz = (float*)Cv + (size_t)bz * zC;
    #pragma unroll
    for (int m = 0; m < 8; ++m) {
      const size_t ri = m0 + wr * 128 + m * 16 + (size_t)((lane >> 4) * 4);
      #pragma unroll
      for (int n = 0; n < 4; ++n) {
        const size_t cj = n0 + wc * 64 + n * 16 + (lane & 15);
        #pragma unroll
        for (int r = 0; r < 4; ++r)
          Cz[(ri + r) * ldc + cj] = acc[m][n][r];
      }
    }
  } else {
    bf16* Cz = (bf16*)Cv + (size_t)bz * zC;
    const float* Sz = scale + (size_t)bz * zS;
    #pragma unroll
    for (int m = 0; m < 8; ++m) {
      const size_t ri = m0 + wr * 128 + m * 16 + (size_t)((lane >> 4) * 4);
      const float4 ik = *reinterpret_cast<const float4*>(Sz + ri);
      #pragma unroll
      for (int n = 0; n < 4; ++n) {
        const size_t cj = n0 + wc * 64 + n * 16 + (lane & 15);
        Cz[(ri + 0) * ldc + cj] = __float2bfloat16(acc[m][n][0] * ik.x);
        Cz[(ri + 1) * ldc + cj] = __float2bfloat16(acc[m][n][1] * ik.y);
        Cz[(ri + 2) * ldc + cj] = __float2bfloat16(acc[m][n][2] * ik.z);
        Cz[(ri + 3) * ldc + cj] = __float2bfloat16(acc[m][n][3] * ik.w);
      }
    }
  }
}

// ---------------- 128x128 NT GEMM (kept for the small x-GEMM) ----------------
__global__ __launch_bounds__(256) void k_gemm_nt(
    const bf16* __restrict__ A, const bf16* __restrict__ B,
    float* __restrict__ C,
    int lda, int ldb, int ldc, int K,
    size_t zA, size_t zB, size_t zC)
{
  __shared__ bf16 As[128 * 32];
  __shared__ bf16 Bs[128 * 32];
  const int tid = threadIdx.x;
  const int lane = tid & 63;
  const int wc = (tid >> 6) & 1;
  const int wr = (tid >> 7) & 1;
  const size_t m0 = (size_t)blockIdx.y * 128;
  const size_t n0 = (size_t)blockIdx.x * 128;
  const bf16* Az = A + (size_t)blockIdx.z * zA;
  const bf16* Bz = B + (size_t)blockIdx.z * zB;
  float* Cz = C + (size_t)blockIdx.z * zC;
  f32x4 acc[4][4] = {};

  const int beta0 = tid * 16;
  const int row0 = tid >> 2;
  const int kk0 = ((tid & 3) ^ ((row0 >> 1) & 3)) * 8;
  const int sw = (((lane >> 4) ^ ((lane >> 1) & 3)) << 4);
  const int rsel = lane & 15;

  for (int k0 = 0; k0 < K; k0 += 32) {
    __syncthreads();
    __builtin_amdgcn_global_load_lds(
        (const __attribute__((address_space(1))) void*)(Az + (m0 + row0) * lda + (k0 + kk0)),
        (__attribute__((address_space(3))) void*)(&As[beta0 / 2]), 16, 0, 0);
    __builtin_amdgcn_global_load_lds(
        (const __attribute__((address_space(1))) void*)(Az + (m0 + row0 + 64) * lda + (k0 + kk0)),
        (__attribute__((address_space(3))) void*)(&As[beta0 / 2 + 2048]), 16, 0, 0);
    __builtin_amdgcn_global_load_lds(
        (const __attribute__((address_space(1))) void*)(Bz + (n0 + row0) * ldb + (k0 + kk0)),
        (__attribute__((address_space(3))) void*)(&Bs[beta0 / 2]), 16, 0, 0);
    __builtin_amdgcn_global_load_lds(
        (const __attribute__((address_space(1))) void*)(Bz + (n0 + row0 + 64) * ldb + (k0 + kk0)),
        (__attribute__((address_space(3))) void*)(&Bs[beta0 / 2 + 2048]), 16, 0, 0);
    __syncthreads();

    v8bf af[4], bg[4];
    #pragma unroll
    for (int m = 0; m < 4; ++m) {
      const int rA = wr * 64 + m * 16 + rsel;
      af[m] = *reinterpret_cast<const v8bf*>(reinterpret_cast<const char*>(As) + rA * 64 + sw);
      const int rB = wc * 64 + m * 16 + rsel;
      bg[m] = *reinterpret_cast<const v8bf*>(reinterpret_cast<const char*>(Bs) + rB * 64 + sw);
    }
    #pragma unroll
    for (int m = 0; m < 4; ++m)
      #pragma unroll
      for (int n = 0; n < 4; ++n)
        acc[m][n] = __builtin_amdgcn_mfma_f32_16x16x32_bf16(af[m], bg[n], acc[m][n], 0, 0, 0);
  }

  #pragma unroll
  for (int m = 0; m < 4; ++m) {
    const size_t ri = m0 + wr * 64 + m * 16 + ((lane >> 4) * 4);
    #pragma unroll
    for (int n = 0; n < 4; ++n) {
      const size_t cj = n0 + wc * 64 + n * 16 + (lane & 15);
      #pragma unroll
      for (int r = 0; r < 4; ++r)
        Cz[(ri + r) * ldc + cj] = acc[m][n][r];
    }
  }
}

// ---- softmax over rows (bf16 scores in, no-max: cosine-bounded), grid-stride ----
__global__ __launch_bounds__(256) void k_softmax(const bf16* __restrict__ sc,
                                                 float* __restrict__ attn,
                                                 bf16* __restrict__ abf) {
  const int wave = ((int)blockIdx.x * 256 + (int)threadIdx.x) >> 6;  // 0..8191
  const int lane = threadIdx.x & 63;
  for (int i = 0; i < 4; ++i) {
    const size_t row = (size_t)wave * 4 + i;
    const u16x8* sr = reinterpret_cast<const u16x8*>(sc + row * Ls);
    const u16x8 s0 = sr[lane], s1 = sr[lane + 64];
    float e[16];
    float ss = 0.f;
    #pragma unroll
    for (int j = 0; j < 8; ++j) { e[j] = __expf(bfbits2f(s0[j])); ss += e[j]; }
    #pragma unroll
    for (int j = 0; j < 8; ++j) { e[8 + j] = __expf(bfbits2f(s1[j])); ss += e[8 + j]; }
    #pragma unroll
    for (int o = 1; o < 64; o <<= 1) ss += __shfl_xor(ss, o);
    const float inv = 1.0f / ss;
    #pragma unroll
    for (int j = 0; j < 16; ++j) e[j] *= inv;
    float4* ar = reinterpret_cast<float4*>(attn + row * Ls);
    float4 a0 = {e[0], e[1], e[2], e[3]},   a1 = {e[4], e[5], e[6], e[7]};
    float4 a2 = {e[8], e[9], e[10], e[11]}, a3 = {e[12], e[13], e[14], e[15]};
    ar[lane * 2 + 0] = a0;  ar[lane * 2 + 1] = a1;
    ar[128 + lane * 2 + 0] = a2;  ar[128 + lane * 2 + 1] = a3;
    u16x8* ab8 = reinterpret_cast<u16x8*>(abf + row * Ls);
    u16x8 b0, b1;
    #pragma unroll
    for (int j = 0; j < 8; ++j) { b0[j] = f2b(e[j]); b1[j] = f2b(e[8 + j]); }
    ab8[lane] = b0;
    ab8[64 + lane] = b1;
  }
}

// ---------------- reduce split-K partials -> A2 = [ah | al | ah] ----------------
__global__ __launch_bounds__(256) void k_reduce(const float* __restrict__ part,
                                                bf16* __restrict__ A2) {
  const size_t idx = (size_t)blockIdx.x * 256 + threadIdx.x;   // over L*D/4
  float4 s = {0.f, 0.f, 0.f, 0.f};
  #pragma unroll
  for (int g = 0; g < 16; ++g) {
    const float4 p = reinterpret_cast<const float4*>(part + (size_t)g * (Ls * Ds))[idx];
    s.x += p.x; s.y += p.y; s.z += p.z; s.w += p.w;
  }
  const size_t e0 = idx * 4;
  const size_t i = e0 >> 10, d = e0 & 1023;
  u16x4 h = { f2b(s.x), f2b(s.y), f2b(s.z), f2b(s.w) };
  u16x4 l = { f2b(s.x - bfbits2f(h[0])), f2b(s.y - bfbits2f(h[1])),
              f2b(s.z - bfbits2f(h[2])), f2b(s.w - bfbits2f(h[3])) };
  bf16* row = A2 + i * 3072;
  *reinterpret_cast<u16x4*>(row + d) = h;
  *reinterpret_cast<u16x4*>(row + 1024 + d) = l;
  *reinterpret_cast<u16x4*>(row + 2048 + d) = h;
}

// ---------------- reduce x split-K partials + bias + relu ----------------
__global__ __launch_bounds__(256) void k_reduce2(const float* __restrict__ part2,
                                                 const float* __restrict__ bias,
                                                 float* __restrict__ xout) {
  const size_t idx = (size_t)blockIdx.x * 256 + threadIdx.x;   // over L*H/4
  float4 s = {0.f, 0.f, 0.f, 0.f};
  #pragma unroll
  for (int g = 0; g < 4; ++g) {
    const float4 p = reinterpret_cast<const float4*>(part2 + (size_t)g * (Ls * Hs))[idx];
    s.x += p.x; s.y += p.y; s.z += p.z; s.w += p.w;
  }
  const size_t h0 = (idx * 4) & 1023;
  const float4 bv = *reinterpret_cast<const float4*>(bias + h0);
  s.x = fmaxf(s.x + bv.x, 0.f); s.y = fmaxf(s.y + bv.y, 0.f);
  s.z = fmaxf(s.z + bv.z, 0.f); s.w = fmaxf(s.w + bv.w, 0.f);
  reinterpret_cast<float4*>(xout)[idx] = s;
}

extern "C" void kernel_launch(void* const* d_in, const int* in_sizes, int n_in,
                              void* d_out, int out_size, void* d_ws, size_t ws_size,
                              hipStream_t stream) {
  const float* q = (const float*)d_in[0];
  const float* k = (const float*)d_in[1];
  const float* W = (const float*)d_in[2];
  const float* bias = (const float*)d_in[3];
  float* xout = (float*)d_out;                        // [1024][1024]
  float* attn = (float*)d_out + (size_t)Ls * Hs;      // [32][1024][1024]

  char* w = (char*)d_ws;
  bf16* qn    = (bf16*)w;                             // 64 MB; reused as abf
  bf16* kb    = (bf16*)(w + ((size_t)64 << 20));      // 64 MB raw keys; reused as part
  bf16* kT    = (bf16*)(w + ((size_t)128 << 20));     // 64 MB; reused as part2
  bf16* sc_bf = (bf16*)(w + ((size_t)192 << 20));     // 64 MB bf16 scores
  bf16* W2    = (bf16*)(w + ((size_t)256 << 20));     // 6 MB
  bf16* A2    = (bf16*)(w + ((size_t)263 << 20));     // 6 MB
  float* invk = (float*)(w + ((size_t)270 << 20));    // 128 KB
  float* part  = (float*)kb;                          // 64 MB (16 groups x 4 MB)
  float* part2 = (float*)kT;                          // 16 MB (4 groups x 4 MB)
  bf16* abf = qn;

  k_convq<<<2048, 256, 0, stream>>>(q, qn);
  k_convkT<<<dim3(16, NBATCH), 256, 0, stream>>>(k, kb, kT, invk);
  k_w2<<<(Hs * Ds / 4) / 256, 256, 0, stream>>>(W, W2);

  // scores[b][i][j] = (kb_b[i,:] . qn_b[j,:]) * invk[b][i] -> bf16 ws
  // flat 512-block grid, XCD-affinity swizzled
  k_gemm256<16, 1><<<512, 512, 0, stream>>>(kb, qn, sc_bf, invk,
      Ds, Ds, Ls, 1,
      (size_t)Ls * Ds, (size_t)Ls * Ds,
      (size_t)Ls * Ds, (size_t)Ls * Ds, (size_t)Ls * Ls, (size_t)Ls);

  k_softmax<<<2048, 256, 0, stream>>>(sc_bf, attn, abf);

  // out partials: 16 z-groups x 2 batches each; flat 256-block grid, swizzled
  k_gemm256<16, 0><<<256, 512, 0, stream>>>(abf, kT, part, nullptr,
      Ls, Ls, Ds, 2,
      (size_t)Ls * Ls, (size_t)Ls * Ds,
      (size_t)2 * Ls * Ls, (size_t)2 * Ls * Ds, (size_t)Ls * Ds, 0);

  k_reduce<<<(Ls * Ds / 4) / 256, 256, 0, stream>>>(part, A2);

  // x partials: split-K over 4 z-groups, K=768 each (A2/W2 are K=3072 hi/lo-split)
  k_gemm_nt<<<dim3(8, 8, 4), 256, 0, stream>>>(A2, W2, part2,
      3072, 3072, Hs, 768, 768, 768, (size_t)Ls * Hs);

  k_reduce2<<<(Ls * Hs / 4) / 256, 256, 0, stream>>>(part2, bias, xout);
}